// Round 1
// baseline (380.856 us; speedup 1.0000x reference)
//
#include <hip/hip_runtime.h>
#include <hip/hip_fp16.h>

// InstantNGP hash-grid encoding, fp32 in/out.
// N_POINTS=1048576, N_LEVELS=16, F=2. SIZES[l]=2^(l+1), OFFS[l]=2^(l+1)-2.
// Hash: h = x*(P1*P2*P3) + y*(P2*P3) + z*P3 (mod 2^32).
//
// R4 result: WRITE_SIZE now exactly output-sized (134 MB), hbm_bytes at the
// hand-computed ideal. Kernel is latency-bound: VALUBusy 34%, LDS-conflict
// ~21%, HBM 13%, occupancy 58% -- no pipe near ceiling.
// R5: 2 points per thread (t and t+BLOCK) = 2x independent gather chains per
// wave at constant occupancy. Both points share q -> single l<=12 branch per
// level (halves divergent-path issue). VGPR 32->~56; __launch_bounds__(1024,8)
// caps at 64 VGPR so 2 blocks/CU (32 waves) is preserved.

#define N_POINTS 1048576
#define BLOCK 1024
#define NBLOCKS 512
#define OUTER 8           // 2 points/thread/iter: NBLOCKS*BLOCK*OUTER*2 == 8*N_POINTS
#define STAGED_ROWS 16382 // levels 0..12
#define LDS_BYTES 65536   // half2 rows

__device__ __forceinline__ float2 ldsRow(const unsigned* __restrict__ lds, unsigned idx) {
    unsigned u = lds[idx];
    __half2 h = *(__half2*)&u;
    return __half22float2(h);
}

__device__ __forceinline__ void prepLevel(
    float px, float py, float pz, float fres,
    unsigned HA, unsigned HB, unsigned HC,
    unsigned& h000, float* w)
{
    const float csx = (px + 1.0f) * fres;
    const float csy = (py + 1.0f) * fres;
    const float csz = (pz + 1.0f) * fres;
    const float cfx = floorf(csx), cfy = floorf(csy), cfz = floorf(csz);
    const float tx = csx - cfx, ty = csy - cfy, tz = csz - cfz;
    h000 = (unsigned)cfx * HA + (unsigned)cfy * HB + (unsigned)cfz * HC;
    const float ux = 1.0f - tx, uy = 1.0f - ty, uz = 1.0f - tz;
    w[0] = ux * uy * uz; w[1] = tx * uy * uz;
    w[2] = ux * ty * uz; w[3] = tx * ty * uz;
    w[4] = ux * uy * tz; w[5] = tx * uy * tz;
    w[6] = ux * ty * tz; w[7] = tx * ty * tz;
}

__global__ __launch_bounds__(BLOCK, 8) void ngp_encode_kernel(
    const float* __restrict__ coords,
    const float* __restrict__ table,
    float* __restrict__ out)
{
    extern __shared__ unsigned lds_tb[];   // STAGED_ROWS half2 rows

    // ---- stage levels 0..12 as fp16 (float4 = 2 rows) ----
    {
        const float4* __restrict__ t4 = (const float4*)table;
        uint2* __restrict__ l2 = (uint2*)lds_tb;
        const int n = STAGED_ROWS / 2;     // 8191
        for (int r = threadIdx.x; r < n; r += BLOCK) {
            float4 v = t4[r];
            __half2 a = __floats2half2_rn(v.x, v.y);
            __half2 b = __floats2half2_rn(v.z, v.w);
            uint2 u;
            u.x = *(unsigned*)&a;
            u.y = *(unsigned*)&b;
            l2[r] = u;
        }
    }
    __syncthreads();

    constexpr unsigned P1 = 2654435761u, P2 = 29675113u, P3 = 123456789u;
    constexpr unsigned HA = P1 * P2 * P3;
    constexpr unsigned HB = P2 * P3;
    constexpr unsigned HC = P3;
    const unsigned D[8] = {0u, HA, HB, HA + HB, HC, HA + HC, HB + HC, HA + HB + HC};

    const float2* __restrict__ tb = (const float2*)table;
    float4* __restrict__ out4 = (float4*)out;

    const int q = threadIdx.x & 7;         // level-pair index, fixed per lane

    for (int it = 0; it < OUTER; ++it) {
        const int t0 = (blockIdx.x * (2 * OUTER) + 2 * it) * BLOCK + threadIdx.x;
        const int t1 = t0 + BLOCK;
        const int p0 = t0 >> 3;            // point indices (8 lanes share each)
        const int p1 = t1 >> 3;

        const float px0 = coords[3 * p0 + 0];
        const float py0 = coords[3 * p0 + 1];
        const float pz0 = coords[3 * p0 + 2];
        const float px1 = coords[3 * p1 + 0];
        const float py1 = coords[3 * p1 + 1];
        const float pz1 = coords[3 * p1 + 2];

        float rf0[4], rf1[4];

#pragma unroll
        for (int e = 0; e < 2; ++e) {
            const int l = 2 * q + e;       // this lane's level (runtime)
            const float fres = (l < 5) ? (float)(16 << l) : 512.0f;

            unsigned h0, h1;
            float w0[8], w1[8];
            prepLevel(px0, py0, pz0, fres, HA, HB, HC, h0, w0);
            prepLevel(px1, py1, pz1, fres, HA, HB, HC, h1, w1);

            const unsigned mask = (2u << l) - 1u;
            const unsigned off  = (2u << l) - 2u;

            float o00 = 0.0f, o01 = 0.0f, o10 = 0.0f, o11 = 0.0f;
            if (l <= 12) {
#pragma unroll
                for (int c = 0; c < 8; ++c) {
                    float2 f = ldsRow(lds_tb, off + ((h0 + D[c]) & mask));
                    o00 += f.x * w0[c];
                    o01 += f.y * w0[c];
                }
#pragma unroll
                for (int c = 0; c < 8; ++c) {
                    float2 f = ldsRow(lds_tb, off + ((h1 + D[c]) & mask));
                    o10 += f.x * w1[c];
                    o11 += f.y * w1[c];
                }
            } else {
#pragma unroll
                for (int c = 0; c < 8; ++c) {
                    float2 f = tb[off + ((h0 + D[c]) & mask)];
                    o00 += f.x * w0[c];
                    o01 += f.y * w0[c];
                }
#pragma unroll
                for (int c = 0; c < 8; ++c) {
                    float2 f = tb[off + ((h1 + D[c]) & mask)];
                    o10 += f.x * w1[c];
                    o11 += f.y * w1[c];
                }
            }
            rf0[2 * e + 0] = o00;
            rf0[2 * e + 1] = o01;
            rf1[2 * e + 0] = o10;
            rf1[2 * e + 1] = o11;
        }

        // float4 #q of point p == float4 #t of the flat output: coalesced,
        // each 64 B line fully covered within one store instruction.
        float4 r0, r1;
        r0.x = rf0[0]; r0.y = rf0[1]; r0.z = rf0[2]; r0.w = rf0[3];
        r1.x = rf1[0]; r1.y = rf1[1]; r1.z = rf1[2]; r1.w = rf1[3];
        out4[t0] = r0;
        out4[t1] = r1;
    }
}

extern "C" void kernel_launch(void* const* d_in, const int* in_sizes, int n_in,
                              void* d_out, int out_size, void* d_ws, size_t ws_size,
                              hipStream_t stream) {
    const float* coords = (const float*)d_in[0];
    const float* table  = (const float*)d_in[1];
    float* out = (float*)d_out;

    hipFuncSetAttribute((const void*)ngp_encode_kernel,
                        hipFuncAttributeMaxDynamicSharedMemorySize,
                        LDS_BYTES);

    ngp_encode_kernel<<<NBLOCKS, BLOCK, LDS_BYTES, stream>>>(coords, table, out);
}

// Round 2
// 238.836 us; speedup vs baseline: 1.5946x; 1.5946x over previous
//
#include <hip/hip_runtime.h>
#include <hip/hip_fp16.h>

// InstantNGP hash-grid encoding, fp32 in/out.
// N_POINTS=1048576, N_LEVELS=16, F=2. SIZES[l]=2^(l+1), OFFS[l]=2^(l+1)-2.
// Hash: h = x*(P1*P2*P3) + y*(P2*P3) + z*P3 (mod 2^32).
//
// R4 (137us dispatch): traffic optimal (WRITE==output, hbm_bytes==ideal);
// latency-bound (VALU 34%, LDS-conflict ~21%, HBM 13%, occ 58%).
// R5 FAILED: 2-pt ILP via helper-fn + w arrays -> SROA defeat -> 537 MB
// scratch spill (WRITE_SIZE 652 MB), dur 272us. Theory untested.
// R6: same 2-pt ILP, spill-proof implementation: weights as const init-list
// arrays computed inline (R4-proven to promote), corner loop interleaves both
// points' gathers, no min-waves launch_bounds so allocator isn't forced to
// spill. Expect VGPR 48-64, WRITE back to 131 MB, dur ~100-115us.

#define N_POINTS 1048576
#define BLOCK 1024
#define NBLOCKS 512
#define OUTER 8           // 2 points/thread/iter: NBLOCKS*BLOCK*OUTER*2 == 8*N_POINTS
#define STAGED_ROWS 16382 // levels 0..12
#define LDS_BYTES 65536   // half2 rows

__device__ __forceinline__ float2 ldsRow(const unsigned* __restrict__ lds, unsigned idx) {
    unsigned u = lds[idx];
    __half2 h = *(__half2*)&u;
    return __half22float2(h);
}

__global__ __launch_bounds__(BLOCK) void ngp_encode_kernel(
    const float* __restrict__ coords,
    const float* __restrict__ table,
    float* __restrict__ out)
{
    extern __shared__ unsigned lds_tb[];   // STAGED_ROWS half2 rows

    // ---- stage levels 0..12 as fp16 (float4 = 2 rows) ----
    {
        const float4* __restrict__ t4 = (const float4*)table;
        uint2* __restrict__ l2 = (uint2*)lds_tb;
        const int n = STAGED_ROWS / 2;     // 8191
        for (int r = threadIdx.x; r < n; r += BLOCK) {
            float4 v = t4[r];
            __half2 a = __floats2half2_rn(v.x, v.y);
            __half2 b = __floats2half2_rn(v.z, v.w);
            uint2 u;
            u.x = *(unsigned*)&a;
            u.y = *(unsigned*)&b;
            l2[r] = u;
        }
    }
    __syncthreads();

    constexpr unsigned P1 = 2654435761u, P2 = 29675113u, P3 = 123456789u;
    constexpr unsigned HA = P1 * P2 * P3;
    constexpr unsigned HB = P2 * P3;
    constexpr unsigned HC = P3;
    const unsigned D[8] = {0u, HA, HB, HA + HB, HC, HA + HC, HB + HC, HA + HB + HC};

    const float2* __restrict__ tb = (const float2*)table;
    float4* __restrict__ out4 = (float4*)out;

    const int q = threadIdx.x & 7;         // level-pair index, fixed per lane

    for (int it = 0; it < OUTER; ++it) {
        const int t0 = (blockIdx.x * (2 * OUTER) + 2 * it) * BLOCK + threadIdx.x;
        const int t1 = t0 + BLOCK;
        const int p0 = t0 >> 3;            // point indices (8 lanes share each)
        const int p1 = t1 >> 3;

        const float px0 = coords[3 * p0 + 0];
        const float py0 = coords[3 * p0 + 1];
        const float pz0 = coords[3 * p0 + 2];
        const float px1 = coords[3 * p1 + 0];
        const float py1 = coords[3 * p1 + 1];
        const float pz1 = coords[3 * p1 + 2];

        float r00, r01, r02, r03;          // point0 result (levels 2q, 2q+1)
        float r10, r11, r12, r13;          // point1 result

#pragma unroll
        for (int e = 0; e < 2; ++e) {
            const int l = 2 * q + e;       // this lane's level (runtime)
            const float fres = (l < 5) ? (float)(16 << l) : 512.0f;

            // ---- point 0: scale, floor, hash, weights (inline, init-list) ----
            const float csx0 = (px0 + 1.0f) * fres;
            const float csy0 = (py0 + 1.0f) * fres;
            const float csz0 = (pz0 + 1.0f) * fres;
            const float cfx0 = floorf(csx0), cfy0 = floorf(csy0), cfz0 = floorf(csz0);
            const float tx0 = csx0 - cfx0, ty0 = csy0 - cfy0, tz0 = csz0 - cfz0;
            const unsigned h0 = (unsigned)cfx0 * HA + (unsigned)cfy0 * HB + (unsigned)cfz0 * HC;
            const float ux0 = 1.0f - tx0, uy0 = 1.0f - ty0, uz0 = 1.0f - tz0;
            const float w0[8] = {ux0*uy0*uz0, tx0*uy0*uz0, ux0*ty0*uz0, tx0*ty0*uz0,
                                 ux0*uy0*tz0, tx0*uy0*tz0, ux0*ty0*tz0, tx0*ty0*tz0};

            // ---- point 1 ----
            const float csx1 = (px1 + 1.0f) * fres;
            const float csy1 = (py1 + 1.0f) * fres;
            const float csz1 = (pz1 + 1.0f) * fres;
            const float cfx1 = floorf(csx1), cfy1 = floorf(csy1), cfz1 = floorf(csz1);
            const float tx1 = csx1 - cfx1, ty1 = csy1 - cfy1, tz1 = csz1 - cfz1;
            const unsigned h1 = (unsigned)cfx1 * HA + (unsigned)cfy1 * HB + (unsigned)cfz1 * HC;
            const float ux1 = 1.0f - tx1, uy1 = 1.0f - ty1, uz1 = 1.0f - tz1;
            const float w1[8] = {ux1*uy1*uz1, tx1*uy1*uz1, ux1*ty1*uz1, tx1*ty1*uz1,
                                 ux1*uy1*tz1, tx1*uy1*tz1, ux1*ty1*tz1, tx1*ty1*tz1};

            const unsigned mask = (2u << l) - 1u;
            const unsigned off  = (2u << l) - 2u;

            float o00 = 0.0f, o01 = 0.0f, o10 = 0.0f, o11 = 0.0f;
            if (l <= 12) {
#pragma unroll
                for (int c = 0; c < 8; ++c) {
                    float2 f0 = ldsRow(lds_tb, off + ((h0 + D[c]) & mask));
                    float2 f1 = ldsRow(lds_tb, off + ((h1 + D[c]) & mask));
                    o00 += f0.x * w0[c];
                    o01 += f0.y * w0[c];
                    o10 += f1.x * w1[c];
                    o11 += f1.y * w1[c];
                }
            } else {
#pragma unroll
                for (int c = 0; c < 8; ++c) {
                    float2 f0 = tb[off + ((h0 + D[c]) & mask)];
                    float2 f1 = tb[off + ((h1 + D[c]) & mask)];
                    o00 += f0.x * w0[c];
                    o01 += f0.y * w0[c];
                    o10 += f1.x * w1[c];
                    o11 += f1.y * w1[c];
                }
            }
            if (e == 0) { r00 = o00; r01 = o01; r10 = o10; r11 = o11; }
            else        { r02 = o00; r03 = o01; r12 = o10; r13 = o11; }
        }

        // float4 #q of point p == float4 #t of the flat output: coalesced,
        // each 64 B line fully covered within one store instruction.
        float4 v0, v1;
        v0.x = r00; v0.y = r01; v0.z = r02; v0.w = r03;
        v1.x = r10; v1.y = r11; v1.z = r12; v1.w = r13;
        out4[t0] = v0;
        out4[t1] = v1;
    }
}

extern "C" void kernel_launch(void* const* d_in, const int* in_sizes, int n_in,
                              void* d_out, int out_size, void* d_ws, size_t ws_size,
                              hipStream_t stream) {
    const float* coords = (const float*)d_in[0];
    const float* table  = (const float*)d_in[1];
    float* out = (float*)d_out;

    hipFuncSetAttribute((const void*)ngp_encode_kernel,
                        hipFuncAttributeMaxDynamicSharedMemorySize,
                        LDS_BYTES);

    ngp_encode_kernel<<<NBLOCKS, BLOCK, LDS_BYTES, stream>>>(coords, table, out);
}